// Round 2
// baseline (3493.024 us; speedup 1.0000x reference)
//
#include <hip/hip_runtime.h>

#define B_ 32
#define C_ 128
#define J_ 24
#define T_ 128
#define Q_ 6
#define K_ 1024
#define JT (J_*T_)          // 3072
#define M_ (B_*JT)          // 98304

#define OUT_QUANT 0
#define OUT_IDX   12582912
#define OUT_LOSS  13172736
#define OUT_PERP  13172737

#define TAU 0.02f

// swizzled transposed A-tile index: [c][row], rotate rows by 4*((c>>2)&15)
__device__ __forceinline__ int aidx(int c, int r) {
    return c * 64 + ((r + ((c >> 2) << 2)) & 63);
}

// ---------------- c2: per-code squared norms ----------------
__global__ __launch_bounds__(256) void c2_kernel(const float* __restrict__ cb,
                                                 float* __restrict__ c2) {
    int wave = (blockIdx.x * blockDim.x + threadIdx.x) >> 6;
    int lane = threadIdx.x & 63;
    if (wave >= Q_ * K_) return;
    const float2 v = reinterpret_cast<const float2*>(cb + (size_t)wave * C_)[lane];
    float s = v.x * v.x + v.y * v.y;
    #pragma unroll
    for (int off = 32; off; off >>= 1) s += __shfl_down(s, off, 64);
    if (lane == 0) c2[wave] = s;
}

// ---------------- transpose x (B,C,J,T) -> res (M,C) ----------------
__global__ __launch_bounds__(256) void transpose_kernel(const float* __restrict__ x,
                                                        float* __restrict__ res) {
    __shared__ float tile[32][33];
    const int tx = threadIdx.x & 31, ty = threadIdx.x >> 5;
    const int jt0 = blockIdx.x * 32;
    const int c0 = blockIdx.y * 32;
    const int b = blockIdx.z;
    const float* xb = x + ((size_t)b * C_ + c0) * JT + jt0;
    #pragma unroll
    for (int i = 0; i < 4; ++i) {
        int cc = ty + 8 * i;
        tile[cc][tx] = xb[(size_t)cc * JT + tx];
    }
    __syncthreads();
    float* rb = res + ((size_t)b * JT + jt0) * C_ + c0;
    #pragma unroll
    for (int i = 0; i < 4; ++i) {
        int jj = ty + 8 * i;
        rb[(size_t)jj * C_ + tx] = tile[tx][jj];
    }
}

// ---------------- argmin over K codes for 64 rows / block ----------------
__global__ __launch_bounds__(256, 2) void argmin_kernel(const float* __restrict__ res,
                                                        const float* __restrict__ cb,
                                                        const float* __restrict__ c2,
                                                        int* __restrict__ idxout, int q) {
    __shared__ __attribute__((aligned(16))) float a_lds[128 * 64];
    __shared__ float r2_lds[64];
    __shared__ float red_d[16 * 64];
    __shared__ float red_d2[16 * 64];
    __shared__ int red_i[16 * 64];
    __shared__ double dred[256];
    __shared__ int dredi[256];
    __shared__ int nflag;
    __shared__ int flaglist[64];

    const int t = threadIdx.x;
    const int m0 = blockIdx.x * 64;
    if (t == 0) nflag = 0;

    // stage A: 64 rows x 128 c, transposed + swizzled
    {
        const float4* src = (const float4*)(res + (size_t)m0 * C_);
        #pragma unroll
        for (int i = 0; i < 8; ++i) {
            int v = t + 256 * i;
            int row = v >> 5;
            int c4 = (v & 31) << 2;
            float4 f = src[v];
            a_lds[aidx(c4 + 0, row)] = f.x;
            a_lds[aidx(c4 + 1, row)] = f.y;
            a_lds[aidx(c4 + 2, row)] = f.z;
            a_lds[aidx(c4 + 3, row)] = f.w;
        }
    }
    __syncthreads();
    if (t < 64) {
        float s = 0.f;
        for (int c = 0; c < 128; ++c) { float v = a_lds[aidx(c, t)]; s += v * v; }
        r2_lds[t] = s;
    }
    __syncthreads();

    const int tr = t & 15, tc = t >> 4;
    const int tr4 = tr << 2;
    float r2r[4];
    #pragma unroll
    for (int r = 0; r < 4; ++r) r2r[r] = r2_lds[tr4 + r];

    float bestd[4] = {3.4e38f, 3.4e38f, 3.4e38f, 3.4e38f};
    float bestd2[4] = {3.4e38f, 3.4e38f, 3.4e38f, 3.4e38f};
    int besti[4] = {0, 0, 0, 0};

    const float* cbq = cb + (size_t)q * K_ * C_;
    const float* c2q = c2 + q * K_;

    for (int kc = 0; kc < 8; ++kc) {
        const int kb = kc * 128 + tc * 8;
        const float* bbase = cbq + (size_t)kb * C_;
        float acc[4][8];
        #pragma unroll
        for (int r = 0; r < 4; ++r)
            #pragma unroll
            for (int kk = 0; kk < 8; ++kk) acc[r][kk] = 0.f;

        #pragma unroll 2
        for (int c4 = 0; c4 < 32; ++c4) {
            float bb[8][4];
            #pragma unroll
            for (int kk = 0; kk < 8; ++kk) {
                float4 v = *(const float4*)(bbase + (size_t)kk * C_ + (c4 << 2));
                bb[kk][0] = v.x; bb[kk][1] = v.y; bb[kk][2] = v.z; bb[kk][3] = v.w;
            }
            const int rowoff = (tr4 + ((c4 & 15) << 2)) & 63;
            #pragma unroll
            for (int j = 0; j < 4; ++j) {
                const float4 av = *(const float4*)&a_lds[((c4 << 2) + j) * 64 + rowoff];
                #pragma unroll
                for (int kk = 0; kk < 8; ++kk) {
                    const float b = bb[kk][j];
                    acc[0][kk] += av.x * b;
                    acc[1][kk] += av.y * b;
                    acc[2][kk] += av.z * b;
                    acc[3][kk] += av.w * b;
                }
            }
        }

        #pragma unroll
        for (int kk = 0; kk < 8; ++kk) {
            const int k = kb + kk;
            const float c2k = c2q[k];
            #pragma unroll
            for (int r = 0; r < 4; ++r) {
                float d = (r2r[r] - 2.0f * acc[r][kk]) + c2k;  // match ref association
                if (d < bestd[r]) {
                    bestd2[r] = bestd[r];
                    bestd[r] = d; besti[r] = k;
                } else if (d < bestd2[r]) {
                    bestd2[r] = d;
                }
            }
        }
    }

    #pragma unroll
    for (int r = 0; r < 4; ++r) {
        red_d[tc * 64 + tr4 + r] = bestd[r];
        red_d2[tc * 64 + tr4 + r] = bestd2[r];
        red_i[tc * 64 + tr4 + r] = besti[r];
    }
    __syncthreads();
    if (t < 64) {
        float D1 = red_d[t];
        float D2 = red_d2[t];
        int I1 = red_i[t];
        #pragma unroll
        for (int tcc = 1; tcc < 16; ++tcc) {
            float d1c = red_d[tcc * 64 + t];
            float d2c = red_d2[tcc * 64 + t];
            int i1c = red_i[tcc * 64 + t];
            if (d1c < D1) {
                D2 = fminf(D1, d2c);
                D1 = d1c; I1 = i1c;   // tc ascending == k ascending: first wins
            } else {
                D2 = fminf(D2, d1c);
            }
        }
        idxout[(size_t)q * M_ + m0 + t] = I1;
        if (D2 - D1 < TAU) {          // near-tie: needs fp64 resolution
            int p = atomicAdd(&nflag, 1);
            flaglist[p] = t;
        }
    }
    __syncthreads();

    // fp64 refinement for flagged rows: recompute all K distances exactly
    for (int f = 0; f < nflag; ++f) {
        const int r = flaglist[f];
        double bd = 1e300; int bk = 0;
        #pragma unroll
        for (int kk = 0; kk < 4; ++kk) {
            const int k = t + kk * 256;
            const float* bp = cbq + (size_t)k * C_;
            double s = 0.0;
            for (int c = 0; c < 128; ++c) {
                double diff = (double)a_lds[aidx(c, r)] - (double)bp[c];
                s = fma(diff, diff, s);
            }
            if (s < bd || (s == bd && k < bk)) { bd = s; bk = k; }
        }
        dred[t] = bd; dredi[t] = bk;
        __syncthreads();
        for (int o = 128; o; o >>= 1) {
            if (t < o) {
                double d2 = dred[t + o]; int k2 = dredi[t + o];
                if (d2 < dred[t] || (d2 == dred[t] && k2 < dredi[t])) {
                    dred[t] = d2; dredi[t] = k2;
                }
            }
            __syncthreads();
        }
        if (t == 0) idxout[(size_t)q * M_ + m0 + r] = dredi[0];
        __syncthreads();
    }
}

// ---------------- residual update + loss partial + histogram ----------------
__global__ __launch_bounds__(256) void update_kernel(float* __restrict__ res,
                                                     const float* __restrict__ cb,
                                                     const int* __restrict__ idxin,
                                                     int* __restrict__ counts,
                                                     float* __restrict__ partials, int q) {
    __shared__ float wsum[4];
    const int t = threadIdx.x;
    const int w = t >> 6, lane = t & 63;
    const int half = lane >> 5, l32 = lane & 31;
    float sq = 0.f;
    const float* cbq = cb + (size_t)q * K_ * C_;
    #pragma unroll
    for (int pass = 0; pass < 8; ++pass) {
        const int m = blockIdx.x * 64 + pass * 8 + w * 2 + half;
        const int k = idxin[(size_t)q * M_ + m];
        const float4 cv = *(const float4*)(cbq + (size_t)k * C_ + l32 * 4);
        float4* rp = (float4*)(res + (size_t)m * C_) + l32;
        float4 rv = *rp;
        // loss uses (residual - xd)
        float dx = rv.x - cv.x, dy = rv.y - cv.y, dz = rv.z - cv.z, dw = rv.w - cv.w;
        sq += dx * dx + dy * dy + dz * dz + dw * dw;
        // replicate STE rounding: quant = r + (xd - r); new_res = r - quant
        float4 nr;
        nr.x = rv.x - (rv.x + (cv.x - rv.x));
        nr.y = rv.y - (rv.y + (cv.y - rv.y));
        nr.z = rv.z - (rv.z + (cv.z - rv.z));
        nr.w = rv.w - (rv.w + (cv.w - rv.w));
        *rp = nr;
        if (l32 == 0) atomicAdd(&counts[q * K_ + k], 1);
    }
    #pragma unroll
    for (int off = 32; off; off >>= 1) sq += __shfl_down(sq, off, 64);
    if (lane == 0) wsum[w] = sq;
    __syncthreads();
    if (t == 0) partials[q * 1536 + blockIdx.x] = wsum[0] + wsum[1] + wsum[2] + wsum[3];
}

// ---------------- scalars: loss + perplexity ----------------
__global__ __launch_bounds__(256) void scalars_kernel(const float* __restrict__ partials,
                                                      const int* __restrict__ counts,
                                                      float* __restrict__ out) {
    __shared__ float red[256];
    const int t = threadIdx.x;
    float loss_acc = 0.f, perp_acc = 0.f;
    for (int q = 0; q < Q_; ++q) {
        float s = 0.f;
        for (int i = t; i < 1536; i += 256) s += partials[q * 1536 + i];
        red[t] = s;
        __syncthreads();
        for (int o = 128; o; o >>= 1) {
            if (t < o) red[t] += red[t + o];
            __syncthreads();
        }
        if (t == 0) loss_acc += red[0] / (float)(M_ * C_);
        __syncthreads();
    }
    for (int q = 0; q < Q_; ++q) {
        float s = 0.f;
        for (int k = t; k < K_; k += 256) {
            float p = (float)counts[q * K_ + k] / (float)M_;
            s += p * logf(p + 1e-10f);
        }
        red[t] = s;
        __syncthreads();
        for (int o = 128; o; o >>= 1) {
            if (t < o) red[t] += red[t + o];
            __syncthreads();
        }
        if (t == 0) perp_acc += expf(-red[0]);
        __syncthreads();
    }
    if (t == 0) {
        out[OUT_LOSS] = loss_acc / (float)Q_;
        out[OUT_PERP] = perp_acc / (float)Q_;
    }
}

// ---------------- quantized_out = x - res_final, back to (B,C,J,T) ----------------
__global__ __launch_bounds__(256) void final_kernel(const float* __restrict__ x,
                                                    const float* __restrict__ res,
                                                    float* __restrict__ out) {
    __shared__ float tile[32][33];
    const int tx = threadIdx.x & 31, ty = threadIdx.x >> 5;
    const int jt0 = blockIdx.x * 32;
    const int c0 = blockIdx.y * 32;
    const int b = blockIdx.z;
    const float* rb = res + ((size_t)b * JT + jt0) * C_ + c0;
    #pragma unroll
    for (int i = 0; i < 4; ++i) {
        int jj = ty + 8 * i;
        tile[jj][tx] = rb[(size_t)jj * C_ + tx];
    }
    __syncthreads();
    const float* xb = x + ((size_t)b * C_ + c0) * JT + jt0;
    float* ob = out + ((size_t)b * C_ + c0) * JT + jt0;
    #pragma unroll
    for (int i = 0; i < 4; ++i) {
        int cc = ty + 8 * i;
        ob[(size_t)cc * JT + tx] = xb[(size_t)cc * JT + tx] - tile[tx][cc];
    }
}

// ---------------- indices (B,J,T,Q) as float ----------------
__global__ __launch_bounds__(256) void idxout_kernel(const int* __restrict__ idxin,
                                                     float* __restrict__ out) {
    int f = blockIdx.x * 256 + threadIdx.x;
    if (f >= M_ * Q_) return;
    int m = f / Q_;
    int q = f - m * Q_;
    out[f] = (float)idxin[q * M_ + m];
}

extern "C" void kernel_launch(void* const* d_in, const int* in_sizes, int n_in,
                              void* d_out, int out_size, void* d_ws, size_t ws_size,
                              hipStream_t stream) {
    const float* x = (const float*)d_in[0];
    const float* cb = (const float*)d_in[1];
    float* out = (float*)d_out;
    char* ws = (char*)d_ws;

    float* res = (float*)ws;                           // 50,331,648 B
    int* idxws = (int*)(ws + 50331648);                //  2,359,296 B
    float* c2 = (float*)(ws + 52690944);               //     24,576 B
    int* counts = (int*)(ws + 52715520);               //     24,576 B
    float* partials = (float*)(ws + 52740096);         //     36,864 B

    hipMemsetAsync(counts, 0, Q_ * K_ * sizeof(int), stream);
    c2_kernel<<<1536, 256, 0, stream>>>(cb, c2);
    transpose_kernel<<<dim3(96, 4, 32), 256, 0, stream>>>(x, res);
    for (int q = 0; q < Q_; ++q) {
        argmin_kernel<<<1536, 256, 0, stream>>>(res, cb, c2, idxws, q);
        update_kernel<<<1536, 256, 0, stream>>>(res, cb, idxws, counts, partials, q);
    }
    scalars_kernel<<<1, 256, 0, stream>>>(partials, counts, out);
    final_kernel<<<dim3(96, 4, 32), 256, 0, stream>>>(x, res, out);
    idxout_kernel<<<2304, 256, 0, stream>>>(idxws, out + OUT_IDX);
}